// Round 4
// baseline (232.788 us; speedup 1.0000x reference)
//
#include <hip/hip_runtime.h>

// PIQuantumDQN: 4-qubit, 5-layer re-uploading circuit, B=524288 samples.
// R15: R14 (scalar, 1 sample/thread) with the launcher fixed: in_sizes[]
// is in ELEMENTS, so B = in_sizes[0]/4 (R14's /16 assumed bytes => only
// 1/4 of outputs written, absmax 0.996).
// Rationale (R14): state re[16]+im[16] = 32 VGPRs, peak live ~60 => 64-reg
// occupancy class: __launch_bounds__(256,8) = 8 waves/SIMD (2x latency
// hiding vs R12/R13), grid 2048 blocks = 8 blocks/CU. Scalar fma (2cyc)
// for one sample == pk fma (4cyc) for two: same cycles/sample, zero
// register pressure.
// Gate forms (R10): RY 3-shear (6 fma/pair), RX tangent (4 fma/pair,
// uniform cos folded into Wu via S^2). CNOTs are register renames.
// wire q (0 = MSB) <-> bit (3-q) of the flat index, so mask(q) = 8 >> q.

__device__ __forceinline__ float rfl(float v) {
    return __uint_as_float(__builtin_amdgcn_readfirstlane(__float_as_uint(v)));
}

// RY via 3 shears on both planes: x-=t*y; y+=s*x; x-=t*y
template<int MASK>
__device__ __forceinline__ void apply_ry_sh(float (&re)[16], float (&im)[16],
                                            float t, float s) {
#pragma unroll
    for (int i0 = 0; i0 < 16; ++i0) {
        if (i0 & MASK) continue;
        const int i1 = i0 | MASK;
        float x, y;
        x = re[i0]; y = re[i1];
        x = x - t * y; y = y + s * x; x = x - t * y;
        re[i0] = x; re[i1] = y;
        x = im[i0]; y = im[i1];
        x = x - t * y; y = y + s * x; x = x - t * y;
        im[i0] = x; im[i1] = y;
    }
}

// RX tangent form; true output = cos(w/2) * (this output), folded into Wu.
template<int MASK>
__device__ __forceinline__ void apply_rx_t(float (&re)[16], float (&im)[16], float t) {
#pragma unroll
    for (int i0 = 0; i0 < 16; ++i0) {
        if (i0 & MASK) continue;
        const int i1 = i0 | MASK;
        float r0 = re[i0], r1 = re[i1];
        float m0 = im[i0], m1 = im[i1];
        re[i0] = t * m1 + r0;
        im[i0] = m0 - t * r1;
        re[i1] = t * m0 + r1;
        im[i1] = m1 - t * r0;
    }
}

template<int CMASK, int TMASK>
__device__ __forceinline__ void apply_cnot(float (&re)[16], float (&im)[16]) {
#pragma unroll
    for (int i = 0; i < 16; ++i) {
        if ((i & CMASK) && !(i & TMASK)) {
            const int j = i | TMASK;
            float tr = re[i]; re[i] = re[j]; re[j] = tr;
            float ti = im[i]; im[i] = im[j]; im[j] = ti;
        }
    }
}

__global__ __launch_bounds__(256, 8) void qdqn_kernel(
    const float* __restrict__ x,        // (B,4) fp32
    const float* __restrict__ weights,  // (5,4) fp32
    const float* __restrict__ Wm,       // (2,4) fp32
    const float* __restrict__ bv,       // (2,)  fp32
    float2* __restrict__ out,           // (B,2) fp32
    int B)
{
    const int t = blockIdx.x * blockDim.x + threadIdx.x;
    if (t >= B) return;

    // ---- issue the x load first so HBM latency overlaps the uniform trig ----
    const float4 x0 = ((const float4*)x)[t];

    // ---- uniforms: tan(w/2) per gate + accumulated scale S = prod cos(w/2) ----
    float tw[20];
    float cp[20];
    const float INV_4PI = 0.07957747154594767f;   // w/2 rad = w*(1/4pi) rev
#pragma unroll
    for (int k = 0; k < 20; ++k) {
        float rev = weights[k] * INV_4PI;         // uniform -> scalar load
        float c = __builtin_amdgcn_cosf(rev);
        float s = __builtin_amdgcn_sinf(rev);
        tw[k] = rfl(s * __builtin_amdgcn_rcpf(c));
        cp[k] = c;
    }
    // pairwise product tree for S (5-deep instead of 20-deep)
    const float S =
        (((cp[0] * cp[1]) * (cp[2] * cp[3])) * ((cp[4] * cp[5]) * (cp[6] * cp[7]))) *
        ((((cp[8] * cp[9]) * (cp[10] * cp[11])) * ((cp[12] * cp[13]) * (cp[14] * cp[15]))) *
         ((cp[16] * cp[17]) * (cp[18] * cp[19])));
    const float S2 = rfl(S) * rfl(S);             // probs scale by S^2
    float Wu[8];
#pragma unroll
    for (int k = 0; k < 8; ++k) Wu[k] = rfl(Wm[k] * S2);   // fold scale here
    const float b0u = rfl(bv[0]);
    const float b1u = rfl(bv[1]);

    // ---- per-sample angle trig ----
    // RY angle phi = xn*pi/2: rev = xn*0.25, |rev|<=0.25.
    // rc=cos(phi)>=0, rs=sin(phi), ryt=tan(phi/2)=rs/(1+rc), |ryt|<=1.
    const float inv_bounds4[4] = { 0.25f / 4.8f, 0.25f / 4.0f, 0.25f / 0.418f, 0.25f / 4.0f };
    const float xv[4] = { x0.x, x0.y, x0.z, x0.w };
    float rc[4], rs[4], ryt[4];
#pragma unroll
    for (int q = 0; q < 4; ++q) {
        float rev = xv[q] * inv_bounds4[q];
        float ra = fminf(fmaxf(rev, -0.25f), 0.25f);
        float sa = __builtin_amdgcn_sinf(ra), ca = __builtin_amdgcn_cosf(ra);
        rs[q] = sa;
        rc[q] = ca;
        ryt[q] = sa * __builtin_amdgcn_rcpf(1.0f + ca);
    }

    // ---- layer 0 (separable until first CNOT), RX part in tangent form ----
    // (1/cw)*RX(w)RY(a)|0> = (alpha,beta): alpha=(ca,-t*sa), beta=(sa,-t*ca)
    // Two-stage kron: t23 = q2(x)q3, k01 = q0(x)q1, amp[(j<<2)|i]=k01[j]*t23[i].
    float re[16], im[16];
    {
        float t23r[4], t23i[4];
        {
            float n2 = -tw[2], n3 = -tw[3];
            float a2r = rc[2], a2i = n2 * rs[2], b2r = rs[2], b2i = n2 * rc[2];
            float a3r = rc[3], a3i = n3 * rs[3], b3r = rs[3], b3i = n3 * rc[3];
#pragma unroll
            for (int j = 0; j < 4; ++j) {
                float xr = (j & 2) ? b2r : a2r, xi = (j & 2) ? b2i : a2i;
                float yr = (j & 1) ? b3r : a3r, yi = (j & 1) ? b3i : a3i;
                t23r[j] = xr * yr - xi * yi;
                t23i[j] = xr * yi + xi * yr;
            }
        }
        float k01r[4], k01i[4];
        {
            float n0 = -tw[0], n1 = -tw[1];
            float a0r = rc[0], a0i = n0 * rs[0], b0r = rs[0], b0i = n0 * rc[0];
            float a1r = rc[1], a1i = n1 * rs[1], b1r = rs[1], b1i = n1 * rc[1];
#pragma unroll
            for (int j = 0; j < 4; ++j) {
                float xr = (j & 2) ? b0r : a0r, xi = (j & 2) ? b0i : a0i;
                float yr = (j & 1) ? b1r : a1r, yi = (j & 1) ? b1i : a1i;
                k01r[j] = xr * yr - xi * yi;
                k01i[j] = xr * yi + xi * yr;
            }
        }
#pragma unroll
        for (int j = 0; j < 4; ++j) {
#pragma unroll
            for (int i = 0; i < 4; ++i) {
                re[(j << 2) | i] = k01r[j] * t23r[i] - k01i[j] * t23i[i];
                im[(j << 2) | i] = k01r[j] * t23i[i] + k01i[j] * t23r[i];
            }
        }
    }
    apply_cnot<8, 4>(re, im);
    apply_cnot<4, 2>(re, im);
    apply_cnot<2, 1>(re, im);
    apply_cnot<1, 8>(re, im);

    // ---- layers 1..4: shear RY (6/pair), tangent RX (4/pair), free CNOTs ----
#pragma unroll
    for (int l = 1; l < 5; ++l) {
        apply_ry_sh<8>(re, im, ryt[0], rs[0]);
        apply_ry_sh<4>(re, im, ryt[1], rs[1]);
        apply_ry_sh<2>(re, im, ryt[2], rs[2]);
        apply_ry_sh<1>(re, im, ryt[3], rs[3]);
        apply_rx_t<8>(re, im, tw[l * 4 + 0]);
        apply_rx_t<4>(re, im, tw[l * 4 + 1]);
        apply_rx_t<2>(re, im, tw[l * 4 + 2]);
        apply_rx_t<1>(re, im, tw[l * 4 + 3]);
        apply_cnot<8, 4>(re, im);
        apply_cnot<4, 2>(re, im);
        apply_cnot<2, 1>(re, im);
        apply_cnot<1, 8>(re, im);
    }

    // ---- probs -> <Z_q> sign tree -> linear layer (scale folded in Wu) ----
    float p[16];
#pragma unroll
    for (int i = 0; i < 16; ++i) p[i] = re[i] * re[i] + im[i] * im[i];
    float tt[8];
#pragma unroll
    for (int i = 0; i < 8; ++i) tt[i] = p[2 * i] + p[2 * i + 1];
    float u[4];
#pragma unroll
    for (int i = 0; i < 4; ++i) u[i] = tt[2 * i] + tt[2 * i + 1];
    const float z0 = (u[0] + u[1]) - (u[2] + u[3]);         // wire 0 (bit 3)
    const float z1 = (u[0] - u[1]) + (u[2] - u[3]);         // wire 1 (bit 2)
    const float z2 = (tt[0] - tt[1]) + (tt[2] - tt[3])
                   + (tt[4] - tt[5]) + (tt[6] - tt[7]);     // wire 2 (bit 1)
    const float z3 = ((p[0] - p[1]) + (p[2] - p[3]))
                   + ((p[4] - p[5]) + (p[6] - p[7]))
                   + ((p[8] - p[9]) + (p[10] - p[11]))
                   + ((p[12] - p[13]) + (p[14] - p[15]));   // wire 3 (bit 0)

    float o0 = b0u, o1 = b1u;
    o0 = Wu[0] * z0 + o0; o0 = Wu[1] * z1 + o0;
    o0 = Wu[2] * z2 + o0; o0 = Wu[3] * z3 + o0;
    o1 = Wu[4] * z0 + o1; o1 = Wu[5] * z1 + o1;
    o1 = Wu[6] * z2 + o1; o1 = Wu[7] * z3 + o1;

    out[t] = make_float2(o0, o1);
}

extern "C" void kernel_launch(void* const* d_in, const int* in_sizes, int n_in,
                              void* d_out, int out_size, void* d_ws, size_t ws_size,
                              hipStream_t stream) {
    const float* x  = (const float*)d_in[0];
    const float* w  = (const float*)d_in[1];
    const float* Wm = (const float*)d_in[2];
    const float* bv = (const float*)d_in[3];
    float2* out = (float2*)d_out;

    const int B = in_sizes[0] / 4;              // in_sizes is ELEMENTS; x is (B,4)
    dim3 grid((B + 255) / 256), block(256);
    qdqn_kernel<<<grid, block, 0, stream>>>(x, w, Wm, bv, out, B);
}

// Round 5
// 97.575 us; speedup vs baseline: 2.3857x; 2.3857x over previous
//
#include <hip/hip_runtime.h>

// PIQuantumDQN: 4-qubit, 5-layer re-uploading circuit, B=524288 samples.
// R16: scalar 1-sample/thread at the 128-VGPR class: __launch_bounds__(256,4).
// R15's (256,8) forced a 64-VGPR budget -> allocator kept 32 arch VGPRs and
// spilled the state: 229 MB FETCH + 461 MB WRITE of scratch traffic, 179 us.
// Occupancy-class calibration so far: 256-cap -> AGPR shuffles (R11, 48us),
// 128-cap -> ~33us (R12/R13), 64-cap -> scratch catastrophe (R15, 179us).
// Scalar state re[16]+im[16] = 32 VGPRs, peak live ~60-75 -> fits 128 with
// scheduler slack (R13's 2-sample v2f sat AT the cap; this sits well under).
// Gate forms (R10): RY 3-shear (6 fma/pair), RX tangent (4 fma/pair,
// uniform cos folded into Wu via S^2). CNOTs are register renames.
// wire q (0 = MSB) <-> bit (3-q) of the flat index, so mask(q) = 8 >> q.

__device__ __forceinline__ float rfl(float v) {
    return __uint_as_float(__builtin_amdgcn_readfirstlane(__float_as_uint(v)));
}

// RY via 3 shears on both planes: x-=t*y; y+=s*x; x-=t*y
template<int MASK>
__device__ __forceinline__ void apply_ry_sh(float (&re)[16], float (&im)[16],
                                            float t, float s) {
#pragma unroll
    for (int i0 = 0; i0 < 16; ++i0) {
        if (i0 & MASK) continue;
        const int i1 = i0 | MASK;
        float x, y;
        x = re[i0]; y = re[i1];
        x = x - t * y; y = y + s * x; x = x - t * y;
        re[i0] = x; re[i1] = y;
        x = im[i0]; y = im[i1];
        x = x - t * y; y = y + s * x; x = x - t * y;
        im[i0] = x; im[i1] = y;
    }
}

// RX tangent form; true output = cos(w/2) * (this output), folded into Wu.
template<int MASK>
__device__ __forceinline__ void apply_rx_t(float (&re)[16], float (&im)[16], float t) {
#pragma unroll
    for (int i0 = 0; i0 < 16; ++i0) {
        if (i0 & MASK) continue;
        const int i1 = i0 | MASK;
        float r0 = re[i0], r1 = re[i1];
        float m0 = im[i0], m1 = im[i1];
        re[i0] = t * m1 + r0;
        im[i0] = m0 - t * r1;
        re[i1] = t * m0 + r1;
        im[i1] = m1 - t * r0;
    }
}

template<int CMASK, int TMASK>
__device__ __forceinline__ void apply_cnot(float (&re)[16], float (&im)[16]) {
#pragma unroll
    for (int i = 0; i < 16; ++i) {
        if ((i & CMASK) && !(i & TMASK)) {
            const int j = i | TMASK;
            float tr = re[i]; re[i] = re[j]; re[j] = tr;
            float ti = im[i]; im[i] = im[j]; im[j] = ti;
        }
    }
}

__global__ __launch_bounds__(256, 4) void qdqn_kernel(
    const float* __restrict__ x,        // (B,4) fp32
    const float* __restrict__ weights,  // (5,4) fp32
    const float* __restrict__ Wm,       // (2,4) fp32
    const float* __restrict__ bv,       // (2,)  fp32
    float2* __restrict__ out,           // (B,2) fp32
    int B)
{
    const int t = blockIdx.x * blockDim.x + threadIdx.x;
    if (t >= B) return;

    // ---- issue the x load first so HBM latency overlaps the uniform trig ----
    const float4 x0 = ((const float4*)x)[t];

    // ---- uniforms: tan(w/2) per gate + accumulated scale S = prod cos(w/2) ----
    float tw[20];
    float cp[20];
    const float INV_4PI = 0.07957747154594767f;   // w/2 rad = w*(1/4pi) rev
#pragma unroll
    for (int k = 0; k < 20; ++k) {
        float rev = weights[k] * INV_4PI;         // uniform -> scalar load
        float c = __builtin_amdgcn_cosf(rev);
        float s = __builtin_amdgcn_sinf(rev);
        tw[k] = rfl(s * __builtin_amdgcn_rcpf(c));
        cp[k] = c;
    }
    // pairwise product tree for S (5-deep instead of 20-deep)
    const float S =
        (((cp[0] * cp[1]) * (cp[2] * cp[3])) * ((cp[4] * cp[5]) * (cp[6] * cp[7]))) *
        ((((cp[8] * cp[9]) * (cp[10] * cp[11])) * ((cp[12] * cp[13]) * (cp[14] * cp[15]))) *
         ((cp[16] * cp[17]) * (cp[18] * cp[19])));
    const float S2 = rfl(S) * rfl(S);             // probs scale by S^2
    float Wu[8];
#pragma unroll
    for (int k = 0; k < 8; ++k) Wu[k] = rfl(Wm[k] * S2);   // fold scale here
    const float b0u = rfl(bv[0]);
    const float b1u = rfl(bv[1]);

    // ---- per-sample angle trig ----
    // RY angle phi = xn*pi/2: rev = xn*0.25, |rev|<=0.25.
    // rc=cos(phi)>=0, rs=sin(phi), ryt=tan(phi/2)=rs/(1+rc), |ryt|<=1.
    const float inv_bounds4[4] = { 0.25f / 4.8f, 0.25f / 4.0f, 0.25f / 0.418f, 0.25f / 4.0f };
    const float xv[4] = { x0.x, x0.y, x0.z, x0.w };
    float rc[4], rs[4], ryt[4];
#pragma unroll
    for (int q = 0; q < 4; ++q) {
        float rev = xv[q] * inv_bounds4[q];
        float ra = fminf(fmaxf(rev, -0.25f), 0.25f);
        float sa = __builtin_amdgcn_sinf(ra), ca = __builtin_amdgcn_cosf(ra);
        rs[q] = sa;
        rc[q] = ca;
        ryt[q] = sa * __builtin_amdgcn_rcpf(1.0f + ca);
    }

    // ---- layer 0 (separable until first CNOT), RX part in tangent form ----
    // (1/cw)*RX(w)RY(a)|0> = (alpha,beta): alpha=(ca,-t*sa), beta=(sa,-t*ca)
    // Two-stage kron: t23 = q2(x)q3, k01 = q0(x)q1, amp[(j<<2)|i]=k01[j]*t23[i].
    float re[16], im[16];
    {
        float t23r[4], t23i[4];
        {
            float n2 = -tw[2], n3 = -tw[3];
            float a2r = rc[2], a2i = n2 * rs[2], b2r = rs[2], b2i = n2 * rc[2];
            float a3r = rc[3], a3i = n3 * rs[3], b3r = rs[3], b3i = n3 * rc[3];
#pragma unroll
            for (int j = 0; j < 4; ++j) {
                float xr = (j & 2) ? b2r : a2r, xi = (j & 2) ? b2i : a2i;
                float yr = (j & 1) ? b3r : a3r, yi = (j & 1) ? b3i : a3i;
                t23r[j] = xr * yr - xi * yi;
                t23i[j] = xr * yi + xi * yr;
            }
        }
        float k01r[4], k01i[4];
        {
            float n0 = -tw[0], n1 = -tw[1];
            float a0r = rc[0], a0i = n0 * rs[0], b0r = rs[0], b0i = n0 * rc[0];
            float a1r = rc[1], a1i = n1 * rs[1], b1r = rs[1], b1i = n1 * rc[1];
#pragma unroll
            for (int j = 0; j < 4; ++j) {
                float xr = (j & 2) ? b0r : a0r, xi = (j & 2) ? b0i : a0i;
                float yr = (j & 1) ? b1r : a1r, yi = (j & 1) ? b1i : a1i;
                k01r[j] = xr * yr - xi * yi;
                k01i[j] = xr * yi + xi * yr;
            }
        }
#pragma unroll
        for (int j = 0; j < 4; ++j) {
#pragma unroll
            for (int i = 0; i < 4; ++i) {
                re[(j << 2) | i] = k01r[j] * t23r[i] - k01i[j] * t23i[i];
                im[(j << 2) | i] = k01r[j] * t23i[i] + k01i[j] * t23r[i];
            }
        }
    }
    apply_cnot<8, 4>(re, im);
    apply_cnot<4, 2>(re, im);
    apply_cnot<2, 1>(re, im);
    apply_cnot<1, 8>(re, im);

    // ---- layers 1..4: shear RY (6/pair), tangent RX (4/pair), free CNOTs ----
#pragma unroll
    for (int l = 1; l < 5; ++l) {
        apply_ry_sh<8>(re, im, ryt[0], rs[0]);
        apply_ry_sh<4>(re, im, ryt[1], rs[1]);
        apply_ry_sh<2>(re, im, ryt[2], rs[2]);
        apply_ry_sh<1>(re, im, ryt[3], rs[3]);
        apply_rx_t<8>(re, im, tw[l * 4 + 0]);
        apply_rx_t<4>(re, im, tw[l * 4 + 1]);
        apply_rx_t<2>(re, im, tw[l * 4 + 2]);
        apply_rx_t<1>(re, im, tw[l * 4 + 3]);
        apply_cnot<8, 4>(re, im);
        apply_cnot<4, 2>(re, im);
        apply_cnot<2, 1>(re, im);
        apply_cnot<1, 8>(re, im);
    }

    // ---- probs -> <Z_q> sign tree -> linear layer (scale folded in Wu) ----
    float p[16];
#pragma unroll
    for (int i = 0; i < 16; ++i) p[i] = re[i] * re[i] + im[i] * im[i];
    float tt[8];
#pragma unroll
    for (int i = 0; i < 8; ++i) tt[i] = p[2 * i] + p[2 * i + 1];
    float u[4];
#pragma unroll
    for (int i = 0; i < 4; ++i) u[i] = tt[2 * i] + tt[2 * i + 1];
    const float z0 = (u[0] + u[1]) - (u[2] + u[3]);         // wire 0 (bit 3)
    const float z1 = (u[0] - u[1]) + (u[2] - u[3]);         // wire 1 (bit 2)
    const float z2 = (tt[0] - tt[1]) + (tt[2] - tt[3])
                   + (tt[4] - tt[5]) + (tt[6] - tt[7]);     // wire 2 (bit 1)
    const float z3 = ((p[0] - p[1]) + (p[2] - p[3]))
                   + ((p[4] - p[5]) + (p[6] - p[7]))
                   + ((p[8] - p[9]) + (p[10] - p[11]))
                   + ((p[12] - p[13]) + (p[14] - p[15]));   // wire 3 (bit 0)

    float o0 = b0u, o1 = b1u;
    o0 = Wu[0] * z0 + o0; o0 = Wu[1] * z1 + o0;
    o0 = Wu[2] * z2 + o0; o0 = Wu[3] * z3 + o0;
    o1 = Wu[4] * z0 + o1; o1 = Wu[5] * z1 + o1;
    o1 = Wu[6] * z2 + o1; o1 = Wu[7] * z3 + o1;

    out[t] = make_float2(o0, o1);
}

extern "C" void kernel_launch(void* const* d_in, const int* in_sizes, int n_in,
                              void* d_out, int out_size, void* d_ws, size_t ws_size,
                              hipStream_t stream) {
    const float* x  = (const float*)d_in[0];
    const float* w  = (const float*)d_in[1];
    const float* Wm = (const float*)d_in[2];
    const float* bv = (const float*)d_in[3];
    float2* out = (float2*)d_out;

    const int B = in_sizes[0] / 4;              // in_sizes is ELEMENTS; x is (B,4)
    dim3 grid((B + 255) / 256), block(256);
    qdqn_kernel<<<grid, block, 0, stream>>>(x, w, Wm, bv, out, B);
}

// Round 6
// 85.057 us; speedup vs baseline: 2.7369x; 1.1472x over previous
//
#include <hip/hip_runtime.h>

// PIQuantumDQN: 4-qubit, 5-layer re-uploading circuit, B=524288 samples.
// R17: PLANE-PACKED v2f — one sample/thread, amp[i] = {re_i, im_i}.
// Session calibration: pk f32 is DOUBLE-rate on gfx950 (R16: scalar 1-sample
// at same occupancy class ran ~1.8x slower than v2f 2-sample => v_pk_*_f32
// is the fast path). RY/CNOT act identically on re/im planes and RX is a
// swizzled fma, so packing planes (not samples) keeps the per-sample pk
// count IDENTICAL to R13 (3 pk/pair RY, 2 pk/pair RX) while halving state
// to 32 VGPRs, peak live ~60. => __launch_bounds__(256,6): 85-VGPR budget,
// 6 waves/SIMD (1.5x R13's latency hiding), ~25 regs slack (no spill;
// R15's 64-cap cliff showed what happens without slack).
// Occupancy ladder measured: 256-cap 76.4 / 128-cap-v2f 74.8 (best) /
// 128-cap-scalar 97.6 / 64-cap 232.8 (scratch).
// Gate forms (R10): RY 3-shear, RX tangent (uniform cos folded into Wu via
// S^2). CNOTs are register renames.
// wire q (0 = MSB) <-> bit (3-q) of the flat index, so mask(q) = 8 >> q.

typedef float v2f __attribute__((ext_vector_type(2)));

__device__ __forceinline__ v2f splat(float x) { return (v2f){x, x}; }

__device__ __forceinline__ float rfl(float v) {
    return __uint_as_float(__builtin_amdgcn_readfirstlane(__float_as_uint(v)));
}

// packed complex multiply: {ar,ai}*{br,bi} = {ar*br - ai*bi, ar*bi + ai*br}
__device__ __forceinline__ v2f cmul(v2f a, v2f b) {
    return (v2f){ a.x * b.x - a.y * b.y, a.x * b.y + a.y * b.x };
}

// RY via 3 shears; same coefficients on both planes => pure v2f ops.
template<int MASK>
__device__ __forceinline__ void apply_ry_sh(v2f (&amp)[16], float t, float s) {
    const v2f tv = splat(t), sv = splat(s);
#pragma unroll
    for (int i0 = 0; i0 < 16; ++i0) {
        if (i0 & MASK) continue;
        const int i1 = i0 | MASK;
        v2f x = amp[i0], y = amp[i1];
        x = x - tv * y; y = y + sv * x; x = x - tv * y;
        amp[i0] = x; amp[i1] = y;
    }
}

// RX tangent form; true output = cos(w/2)*(this), folded into Wu.
// amp[i0] += t*{im1,-re1}; amp[i1] += t*{im0,-re0}  (old values)
template<int MASK>
__device__ __forceinline__ void apply_rx_t(v2f (&amp)[16], float t) {
    const v2f tv = splat(t);
#pragma unroll
    for (int i0 = 0; i0 < 16; ++i0) {
        if (i0 & MASK) continue;
        const int i1 = i0 | MASK;
        v2f a0 = amp[i0], a1 = amp[i1];
        v2f s1 = (v2f){ a1.y, -a1.x };   // swap + neg_hi => pk modifiers
        v2f s0 = (v2f){ a0.y, -a0.x };
        amp[i0] = tv * s1 + a0;
        amp[i1] = tv * s0 + a1;
    }
}

template<int CMASK, int TMASK>
__device__ __forceinline__ void apply_cnot(v2f (&amp)[16]) {
#pragma unroll
    for (int i = 0; i < 16; ++i) {
        if ((i & CMASK) && !(i & TMASK)) {
            const int j = i | TMASK;
            v2f tr = amp[i]; amp[i] = amp[j]; amp[j] = tr;
        }
    }
}

__global__ __launch_bounds__(256, 6) void qdqn_kernel(
    const float* __restrict__ x,        // (B,4) fp32
    const float* __restrict__ weights,  // (5,4) fp32
    const float* __restrict__ Wm,       // (2,4) fp32
    const float* __restrict__ bv,       // (2,)  fp32
    float2* __restrict__ out,           // (B,2) fp32
    int B)
{
    const int t = blockIdx.x * blockDim.x + threadIdx.x;
    if (t >= B) return;

    // ---- issue the x load first so HBM latency overlaps the uniform trig ----
    const float4 x0 = ((const float4*)x)[t];

    // ---- uniforms: tan(w/2) per gate + accumulated scale S = prod cos(w/2) ----
    float tw[20];
    float cp[20];
    const float INV_4PI = 0.07957747154594767f;   // w/2 rad = w*(1/4pi) rev
#pragma unroll
    for (int k = 0; k < 20; ++k) {
        float rev = weights[k] * INV_4PI;         // uniform -> scalar load
        float c = __builtin_amdgcn_cosf(rev);
        float s = __builtin_amdgcn_sinf(rev);
        tw[k] = rfl(s * __builtin_amdgcn_rcpf(c));
        cp[k] = c;
    }
    // pairwise product tree for S (5-deep instead of 20-deep)
    const float S =
        (((cp[0] * cp[1]) * (cp[2] * cp[3])) * ((cp[4] * cp[5]) * (cp[6] * cp[7]))) *
        ((((cp[8] * cp[9]) * (cp[10] * cp[11])) * ((cp[12] * cp[13]) * (cp[14] * cp[15]))) *
         ((cp[16] * cp[17]) * (cp[18] * cp[19])));
    const float S2 = rfl(S) * rfl(S);             // probs scale by S^2
    float Wu[8];
#pragma unroll
    for (int k = 0; k < 8; ++k) Wu[k] = rfl(Wm[k] * S2);   // fold scale here
    const float b0u = rfl(bv[0]);
    const float b1u = rfl(bv[1]);

    // ---- per-sample angle trig ----
    // RY angle phi = xn*pi/2: rev = xn*0.25, |rev|<=0.25.
    // rc=cos(phi)>=0, rs=sin(phi), ryt=tan(phi/2)=rs/(1+rc), |ryt|<=1.
    const float inv_bounds4[4] = { 0.25f / 4.8f, 0.25f / 4.0f, 0.25f / 0.418f, 0.25f / 4.0f };
    const float xv[4] = { x0.x, x0.y, x0.z, x0.w };
    float rc[4], rs[4], ryt[4];
#pragma unroll
    for (int q = 0; q < 4; ++q) {
        float rev = xv[q] * inv_bounds4[q];
        float ra = fminf(fmaxf(rev, -0.25f), 0.25f);
        float sa = __builtin_amdgcn_sinf(ra), ca = __builtin_amdgcn_cosf(ra);
        rs[q] = sa;
        rc[q] = ca;
        ryt[q] = sa * __builtin_amdgcn_rcpf(1.0f + ca);
    }

    // ---- layer 0 (separable until first CNOT), RX part in tangent form ----
    // (1/cw)*RX(w)RY(a)|0> = (alpha,beta): alpha={ca,-t*sa}, beta={sa,-t*ca}
    // Two-stage kron: t23 = q2(x)q3, k01 = q0(x)q1, amp[(j<<2)|i]=k01[j]*t23[i].
    v2f amp[16];
    {
        v2f A2 = (v2f){ rc[2], -tw[2] * rs[2] }, B2 = (v2f){ rs[2], -tw[2] * rc[2] };
        v2f A3 = (v2f){ rc[3], -tw[3] * rs[3] }, B3 = (v2f){ rs[3], -tw[3] * rc[3] };
        v2f t23[4];
#pragma unroll
        for (int j = 0; j < 4; ++j)
            t23[j] = cmul((j & 2) ? B2 : A2, (j & 1) ? B3 : A3);

        v2f A0 = (v2f){ rc[0], -tw[0] * rs[0] }, B0 = (v2f){ rs[0], -tw[0] * rc[0] };
        v2f A1 = (v2f){ rc[1], -tw[1] * rs[1] }, B1 = (v2f){ rs[1], -tw[1] * rc[1] };
        v2f k01[4];
#pragma unroll
        for (int j = 0; j < 4; ++j)
            k01[j] = cmul((j & 2) ? B0 : A0, (j & 1) ? B1 : A1);

#pragma unroll
        for (int j = 0; j < 4; ++j)
#pragma unroll
            for (int i = 0; i < 4; ++i)
                amp[(j << 2) | i] = cmul(k01[j], t23[i]);
    }
    apply_cnot<8, 4>(amp);
    apply_cnot<4, 2>(amp);
    apply_cnot<2, 1>(amp);
    apply_cnot<1, 8>(amp);

    // ---- layers 1..4: shear RY (3 pk/pair), tangent RX (2 pk/pair) ----
#pragma unroll
    for (int l = 1; l < 5; ++l) {
        apply_ry_sh<8>(amp, ryt[0], rs[0]);
        apply_ry_sh<4>(amp, ryt[1], rs[1]);
        apply_ry_sh<2>(amp, ryt[2], rs[2]);
        apply_ry_sh<1>(amp, ryt[3], rs[3]);
        apply_rx_t<8>(amp, tw[l * 4 + 0]);
        apply_rx_t<4>(amp, tw[l * 4 + 1]);
        apply_rx_t<2>(amp, tw[l * 4 + 2]);
        apply_rx_t<1>(amp, tw[l * 4 + 3]);
        apply_cnot<8, 4>(amp);
        apply_cnot<4, 2>(amp);
        apply_cnot<2, 1>(amp);
        apply_cnot<1, 8>(amp);
    }

    // ---- probs -> <Z_q> sign tree -> linear layer (scale folded in Wu) ----
    float p[16];
#pragma unroll
    for (int i = 0; i < 16; ++i) p[i] = amp[i].x * amp[i].x + amp[i].y * amp[i].y;
    float tt[8];
#pragma unroll
    for (int i = 0; i < 8; ++i) tt[i] = p[2 * i] + p[2 * i + 1];
    float u[4];
#pragma unroll
    for (int i = 0; i < 4; ++i) u[i] = tt[2 * i] + tt[2 * i + 1];
    const float z0 = (u[0] + u[1]) - (u[2] + u[3]);         // wire 0 (bit 3)
    const float z1 = (u[0] - u[1]) + (u[2] - u[3]);         // wire 1 (bit 2)
    const float z2 = (tt[0] - tt[1]) + (tt[2] - tt[3])
                   + (tt[4] - tt[5]) + (tt[6] - tt[7]);     // wire 2 (bit 1)
    const float z3 = ((p[0] - p[1]) + (p[2] - p[3]))
                   + ((p[4] - p[5]) + (p[6] - p[7]))
                   + ((p[8] - p[9]) + (p[10] - p[11]))
                   + ((p[12] - p[13]) + (p[14] - p[15]));   // wire 3 (bit 0)

    float o0 = b0u, o1 = b1u;
    o0 = Wu[0] * z0 + o0; o0 = Wu[1] * z1 + o0;
    o0 = Wu[2] * z2 + o0; o0 = Wu[3] * z3 + o0;
    o1 = Wu[4] * z0 + o1; o1 = Wu[5] * z1 + o1;
    o1 = Wu[6] * z2 + o1; o1 = Wu[7] * z3 + o1;

    out[t] = make_float2(o0, o1);
}

extern "C" void kernel_launch(void* const* d_in, const int* in_sizes, int n_in,
                              void* d_out, int out_size, void* d_ws, size_t ws_size,
                              hipStream_t stream) {
    const float* x  = (const float*)d_in[0];
    const float* w  = (const float*)d_in[1];
    const float* Wm = (const float*)d_in[2];
    const float* bv = (const float*)d_in[3];
    float2* out = (float2*)d_out;

    const int B = in_sizes[0] / 4;              // in_sizes is ELEMENTS; x is (B,4)
    dim3 grid((B + 255) / 256), block(256);
    qdqn_kernel<<<grid, block, 0, stream>>>(x, w, Wm, bv, out, B);
}